// Round 18
// baseline (147.554 us; speedup 1.0000x reference)
//
#include <hip/hip_runtime.h>

#define VOCAB 53
#define EDIM  16
#define H     32
#define SEQ   512
#define BATCH 4096
#define LOG2E 1.4426950408889634f
#define XRS   132   // xg row stride in f32 words (%4==0 for b128 alignment)
#define HS    72    // h-buffer per-col stride in f16
#define RSC   2048.0f      // weight-residual scale (2^11): lo stays f16-normal
#define RSCI  (1.0f/2048.0f)

typedef _Float16 f16x8 __attribute__((ext_vector_type(8)));
typedef float f32x4 __attribute__((ext_vector_type(4)));

__device__ __forceinline__ float exp2_hw(float x) {
    float r; asm("v_exp_f32 %0, %1" : "=v"(r) : "v"(x)); return r;
}
// rcp(1 + 2^xs): sigmoid when xs = -log2e * z (scales pre-folded into tables)
__device__ __forceinline__ float sig_exp2(float xs) {
    return __builtin_amdgcn_rcpf(1.0f + exp2_hw(xs));
}

// permuted row rp = 16*m + 4*s + g  <->  original W row g*32 + (4m+s)
// (mfma chunk m gives lane (q,c) the 4 gates i,f,g,o of unit 4m+q in D[0..3])
__device__ __forceinline__ void decode_row(int rp, int& orig, float& scale) {
    int m = rp >> 4, rem = rp & 15, s = rem >> 2, g = rem & 3;
    orig = g * 32 + 4 * m + s;
    scale = (g == 2) ? (-2.0f * LOG2E) : (-LOG2E);   // g doubled: tanh(g)=2*sig(2g)-1
}

// 256 blocks x 512 threads (8 waves) — R16 structure with ONE change: the
// in-loop barrier is lgkm-only (s_waitcnt lgkmcnt(0) + s_barrier in one asm
// block) instead of __syncthreads(). __syncthreads' implicit vmcnt(0) was
// draining the s+2 token global prefetch inside every step (~180 cyc serial);
// LDS ordering (h-exchange, xg reads) only needs lgkmcnt. Weight residual
// (Alo, x2048 f16) kept: 2 independent MFMAs, z = D + Dra/2048. h is f16-only
// (random ~1e-4/step error, contractive recurrence — measured absmax 0.0).
__global__ __launch_bounds__(512, 1)
void lstm_seq_classifier(const int* __restrict__ x,
                         const float* __restrict__ emb,
                         const float* __restrict__ W_ih,
                         const float* __restrict__ W_hh,
                         const float* __restrict__ b_ih,
                         const float* __restrict__ b_hh,
                         const float* __restrict__ W_fc,
                         const float* __restrict__ b_fc,
                         float* __restrict__ out) {
    __shared__ float xg_perm[VOCAB * XRS];                  // 27,984 B (f32 exact)
    __shared__ _Float16 whi[128 * 32];                      // 8,192 B
    __shared__ _Float16 wlo[128 * 32];                      // 8,192 B (x2048 residual)
    __shared__ __align__(16) _Float16 hhi_buf[2][16][HS];   // 4,608 B
    __shared__ float red[16 * 33];                          // 2,112 B

    const int tid  = threadIdx.x;
    const int lane = tid & 63;
    const int w    = tid >> 6;      // wave index = mfma row-chunk m
    const int col  = lane & 15;     // batch column
    const int q    = lane >> 4;

    // ---- vocab -> permuted, scaled gate-preactivation table (f32 exact) ----
    for (int idx = tid; idx < VOCAB * 128; idx += 512) {
        int v = idx >> 7, rp = idx & 127;
        int orig; float scale; decode_row(rp, orig, scale);
        float acc = b_ih[orig] + b_hh[orig];
        const float* ev = emb + v * EDIM;
        const float* wr = W_ih + orig * EDIM;
#pragma unroll
        for (int e = 0; e < EDIM; ++e) acc += ev[e] * wr[e];
        xg_perm[v * XRS + rp] = scale * acc;
    }
    // ---- permuted scaled W_hh as f16 hi + scaled f16 residual ----
    for (int idx = tid; idx < 128 * 32; idx += 512) {
        int rp = idx >> 5, k = idx & 31;
        int orig; float scale; decode_row(rp, orig, scale);
        float wv = scale * W_hh[orig * H + k];
        _Float16 hi = (_Float16)wv;
        whi[idx] = hi;
        wlo[idx] = (_Float16)((wv - (float)hi) * RSC);
    }
    for (int idx = tid; idx < 2 * 16 * HS; idx += 512)
        (&hhi_buf[0][0][0])[idx] = (_Float16)0.f;
    __syncthreads();

    // A fragments: chunk-row = col, k-slot j = unit 8q+j (identity k-order)
    const f16x8 Ahi = *reinterpret_cast<const f16x8*>(&whi[(16 * w + col) * 32 + 8 * q]);
    const f16x8 Alo = *reinterpret_cast<const f16x8*>(&wlo[(16 * w + col) * 32 + 8 * q]);

    const long xb = (long)(blockIdx.x * 16 + col) * SEQ;
    const int xoff = 16 * w + 4 * q;
    int vc = x[xb + 1];
    f32x4 xg_cur = *reinterpret_cast<const f32x4*>(&xg_perm[x[xb] * XRS + xoff]);

    float ccs = 0.0f, h = 0.0f;   // ccs = -2log2e * c
    const f32x4 zeroC = {0.f, 0.f, 0.f, 0.f};

    for (int s = 0; s < SEQ; ++s) {
        int vn = x[xb + ((s + 2) & (SEQ - 1))];                      // prefetch s+2
        f32x4 xg_nxt = *reinterpret_cast<const f32x4*>(
            &xg_perm[vc * XRS + xoff]);                              // prefetch s+1
        const int rb = s & 1, nb = rb ^ 1;
        f16x8 Bhi = *reinterpret_cast<const f16x8*>(&hhi_buf[rb][col][8 * q]);

        // two INDEPENDENT MFMAs (1-deep chain), then combine
        f32x4 D   = __builtin_amdgcn_mfma_f32_16x16x32_f16(Ahi, Bhi, xg_cur, 0, 0, 0);
        f32x4 Dra = __builtin_amdgcn_mfma_f32_16x16x32_f16(Alo, Bhi, zeroC, 0, 0, 0);

        float zi = __builtin_fmaf(RSCI, Dra[0], D[0]);
        float zf = __builtin_fmaf(RSCI, Dra[1], D[1]);
        float zg = __builtin_fmaf(RSCI, Dra[2], D[2]);
        float zo = __builtin_fmaf(RSCI, Dra[3], D[3]);

        float si = sig_exp2(zi);                         // sigma(i)
        float sf = sig_exp2(zf);                         // sigma(f)
        float ug = sig_exp2(zg);                         // sigma(2g)
        float so = sig_exp2(zo);                         // sigma(o)
        float t1 = __builtin_fmaf(-4.0f * LOG2E, ug, 2.0f * LOG2E);  // -2l2e*tanh(g)
        ccs = __builtin_fmaf(sf, ccs, si * t1);          // scaled cell
        float tc = __builtin_fmaf(2.0f, sig_exp2(ccs), -1.0f);       // tanh(c)
        h = so * tc;

        hhi_buf[nb][col][4 * w + q] = (_Float16)h;

        // lgkm-only barrier: orders all LDS ops; token prefetch (vmcnt) stays
        // in flight across the barrier (no __syncthreads vmcnt(0) drain)
        asm volatile("s_waitcnt lgkmcnt(0)\n\ts_barrier" ::: "memory");

        xg_cur = xg_nxt;
        vc = vn;
    }

    // ---- final FC (1 unit) + sigmoid: cross-wave reduce over the 32 units ----
    red[col * 33 + 4 * w + q] = h * W_fc[4 * w + q];
    __syncthreads();
    if (w == 0) {
        const float* rr = &red[col * 33];
        float p = 0.f;
#pragma unroll
        for (int u = 0; u < 8; ++u) p += rr[8 * q + u];
        p += __shfl_xor(p, 16);
        p += __shfl_xor(p, 32);
        if (lane < 16) {
            out[blockIdx.x * 16 + col] = sig_exp2(-LOG2E * (p + b_fc[0]));
        }
    }
}

extern "C" void kernel_launch(void* const* d_in, const int* in_sizes, int n_in,
                              void* d_out, int out_size, void* d_ws, size_t ws_size,
                              hipStream_t stream) {
    const int*   x    = (const int*)d_in[0];
    const float* emb  = (const float*)d_in[1];
    const float* W_ih = (const float*)d_in[2];
    const float* W_hh = (const float*)d_in[3];
    const float* b_ih = (const float*)d_in[4];
    const float* b_hh = (const float*)d_in[5];
    const float* W_fc = (const float*)d_in[6];
    const float* b_fc = (const float*)d_in[7];
    float* out = (float*)d_out;

    dim3 grid(BATCH / 16);   // 256 blocks: one 16-elem group per block (1/CU)
    dim3 block(512);         // 8 waves, one mfma row-chunk each
    lstm_seq_classifier<<<grid, block, 0, stream>>>(x, emb, W_ih, W_hh,
                                                    b_ih, b_hh, W_fc, b_fc, out);
}